// Round 9
// baseline (4315.067 us; speedup 1.0000x reference)
//
#include <hip/hip_runtime.h>
#include <cfloat>
#include <math.h>

#define NOBS   256
#define NY     50
#define NX     30
#define NITER  400
#define LRATE  0.05f
#define CSTR   260     // ep_t column stride (floats), init staging
#define THRANK 40      // theta tracks the rank-40 KEY -> C = 41 every valid iter
#define WSLOT  16      // candidate slots per 64-obs window (overflow -> exact fallback)

__device__ __forceinline__ float rl_f(float x, int k) {
  return __int_as_float(__builtin_amdgcn_readlane(__float_as_int(x), k));
}
__device__ __forceinline__ unsigned long long rl_u64(unsigned long long x, int k) {
  const unsigned lo = (unsigned)__builtin_amdgcn_readlane((int)(unsigned)(x & 0xffffffffull), k);
  const unsigned hi = (unsigned)__builtin_amdgcn_readlane((int)(unsigned)(x >> 32), k);
  return ((unsigned long long)hi << 32) | lo;
}

#define DPP_MAXSTEP(x, ctrl)                                                       \
  x = fmaxf(x, __int_as_float(__builtin_amdgcn_update_dpp(                         \
        __float_as_int(x), __float_as_int(x), (ctrl), 0xF, 0xF, false)))

// One scenario/block over 8 waves (2/SIMD). Thread owns obs (tid&255) with the FULL
// 50-wide residual row in registers; halves A/B are bit-identical replicas except:
// A publishes keys/candidates/counts, and backward splits obs windows A/B.
// 3 barriers/iter (was 6): R8 showed each barrier+LDS round-trip costs >> the
// replicated VALU that removing it requires.
__global__ __launch_bounds__(512) __attribute__((amdgpu_waves_per_eu(2, 2)))
void dro_kernel(
    const float* __restrict__ X, const float* __restrict__ Y,
    const float* __restrict__ W, const float* __restrict__ Bb,
    const float* __restrict__ DLT, const float* __restrict__ GMM,
    float* __restrict__ out)
{
  __shared__ __align__(16) float ep_t[51 * CSTR];          // init staging (dead after epb load)
  __shared__ __align__(16) unsigned long long rrk[NOBS];   // full keys (exact fallback)
  __shared__ __align__(16) unsigned long long ckey[64];    // 4 windows x 16 slots (+sentinels)
  __shared__ __align__(16) float red[64];                  // atomic backward reduction
  __shared__ float wmax4[4];
  __shared__ int   vcnt4[4];                               // candidates per window
  __shared__ int   tcnt4[4];                               // max-ties per window
  __shared__ unsigned long long th_key;

  const int tid  = threadIdx.x;      // 0..511
  const int oid  = tid & 255;        // owned observation
  const int half = tid >> 8;         // 0 = A (publisher), 1 = B (replica)
  const int lane = tid & 63;
  const int w8   = tid >> 6;         // wave 0..7
  const int wsc  = w8 & 3;           // obs window (obs wsc*64 + lane)
  const int t    = blockIdx.x;       // scenario

  const float delta = DLT[0];
  const float gamma = GMM[0];
  const float a     = fminf(delta * 0.5f, 255.0f / 256.0f);
  const float a256  = a * 256.0f;

  // ---- init: FULL residual row er[50] for owned obs; stage ep for epb ----
  float er[NY];
  {
    float xr[NX];
    #pragma unroll
    for (int k = 0; k < NX; ++k) xr[k] = X[oid * NX + k];
    for (int j = 0; j < NY; ++j) {                 // W/B wave-uniform -> scalar loads
      float acc = Bb[j];
      #pragma unroll
      for (int k = 0; k < NX; ++k) acc = fmaf(xr[k], W[j * NX + k], acc);
      er[j] = Y[oid * NY + j] - acc;
    }
    if (half == 0) {
      for (int j = 0; j < 25; ++j) ep_t[j * CSTR + oid] = er[j];
    } else {
      for (int j = 25; j < NY; ++j) ep_t[j * CSTR + oid] = er[j];
      ep_t[NY * CSTR + oid] = 1.0f;                // ones column -> c gradient
    }
  }
  float yhl;                                       // y_hat row t, per-lane copy
  {
    const int jr = (lane < NY) ? lane : 0;
    float acc = Bb[jr];
    #pragma unroll
    for (int k = 0; k < NX; ++k) acc = fmaf(X[t * NX + k], W[jr * NX + k], acc);
    yhl = acc;
    if (tid < NY) out[NOBS * NY + t * NY + tid] = acc;
  }
  if (tid == 0) th_key = ~0ull;                    // iter 0 -> exact fallback
  if (tid < 64) ckey[tid] = ~0ull;
  __syncthreads();

  // epb: iteration-invariant backward slice in registers.
  // Wave (half,wsc), lane l: column min(l,50), obs [wsc*64 + half*32, +32).
  float epb[32];
  {
    const int colc = (lane < 51) ? lane : 50;
    const float* ebase = &ep_t[colc * CSTR + wsc * 64 + half * 32];
    #pragma unroll
    for (int q = 0; q < 8; ++q) {
      const float4 e4 = *(const float4*)&ebase[4 * q];
      epb[4*q+0] = e4.x; epb[4*q+1] = e4.y; epb[4*q+2] = e4.z; epb[4*q+3] = e4.w;
    }
  }

  float zv = (lane < NY) ? (1.0f / NY) : 0.0f;     // z one entry/lane, replicated per wave
  float cc = 0.0f;                                 // c, wave-uniform, bit-identical everywhere

  #pragma unroll 1
  for (int it = 0; it < NITER; ++it) {
    // ---- P0: forward from OWN registers (no LDS); key; window max; candidates ----
    const unsigned long long thk = th_key;         // written P1 prev iter; B2+B3 separate
    float u0 = 0.f, u1 = 0.f, u2 = 0.f, u3 = 0.f;
    #pragma unroll
    for (int j = 0; j < 48; j += 4) {
      u0 = fmaf(er[j + 0], rl_f(zv, j + 0), u0);
      u1 = fmaf(er[j + 1], rl_f(zv, j + 1), u1);
      u2 = fmaf(er[j + 2], rl_f(zv, j + 2), u2);
      u3 = fmaf(er[j + 3], rl_f(zv, j + 3), u3);
    }
    u0 = fmaf(er[48], rl_f(zv, 48), u0);
    u1 = fmaf(er[49], rl_f(zv, 49), u1);
    const float u = ((u0 + u2) + (u1 + u3)) - cc;  // bit-identical A/B
    const float r = u * u;
    const unsigned long long key =
        ((unsigned long long)(unsigned)__float_as_int(r) << 32) | (unsigned)oid;
    if (half == 0) rrk[oid] = key;

    float m = r;                                   // window max (lanes cover obs window)
    DPP_MAXSTEP(m, 0x111); DPP_MAXSTEP(m, 0x112);
    DPP_MAXSTEP(m, 0x114); DPP_MAXSTEP(m, 0x118);
    DPP_MAXSTEP(m, 0x142); DPP_MAXSTEP(m, 0x143);
    if (half == 0 && lane == 63) wmax4[wsc] = m;

    const bool cond = (key <= thk);
    const unsigned long long cmask = __ballot(cond);
    const int cpos = __popcll(cmask & ((1ull << lane) - 1ull));
    if (half == 0 && lane == 0) vcnt4[wsc] = __popcll(cmask);
    if (half == 0 && cond && cpos < WSLOT) ckey[wsc * WSLOT + cpos] = key;  // fixed slots
    __syncthreads();                               // B1

    // ---- P1: validity; global max ties; rank scan; theta ----
    const int v0 = vcnt4[0], v1 = vcnt4[1], v2 = vcnt4[2], v3 = vcnt4[3];
    const int C  = v0 + v1 + v2 + v3;
    const bool ovf   = (v0 > WSLOT) | (v1 > WSLOT) | (v2 > WSLOT) | (v3 > WSLOT);
    const bool valid = (!ovf) && ((float)C >= a256);

    const float mx = fmaxf(fmaxf(wmax4[0], wmax4[1]), fmaxf(wmax4[2], wmax4[3]));
    const bool ismax = (r == mx);
    const unsigned long long mmask = __ballot(ismax);   // all lanes (R3 lesson)
    if (half == 0 && lane == 0) tcnt4[wsc] = __popcll(mmask);
    if (w8 == 1) red[lane] = 0.0f;                 // zero reduction buffer (single wave)

    int cnt;
    if (__builtin_expect(valid, 1)) {
      const unsigned long long ck = ckey[lane];    // all 64 slots lane-held; 1 ds_read_b64
      int ch0 = 0, ch1 = 0, ch2 = 0, ch3 = 0;
      #pragma unroll
      for (int s = 0; s < 64; s += 4) {            // sentinels never count
        ch0 += (rl_u64(ck, s + 0) < key) ? 1 : 0;
        ch1 += (rl_u64(ck, s + 1) < key) ? 1 : 0;
        ch2 += (rl_u64(ck, s + 2) < key) ? 1 : 0;
        ch3 += (rl_u64(ck, s + 3) < key) ? 1 : 0;
      }
      cnt = (ch0 + ch2) + (ch1 + ch3);             // cand: exact rank; non-cand: C (>=aN)
    } else {                                       // iter 0 / overflow: exact full scan
      int ch0 = 0, ch1 = 0, ch2 = 0, ch3 = 0;
      const ulonglong2* p = (const ulonglong2*)&rrk[0];
      #pragma unroll 8
      for (int j = 0; j < 128; j += 2) {
        const ulonglong2 ka = p[j], kb = p[j + 1];
        ch0 += (ka.x < key) ? 1 : 0;
        ch1 += (ka.y < key) ? 1 : 0;
        ch2 += (kb.x < key) ? 1 : 0;
        ch3 += (kb.y < key) ? 1 : 0;
      }
      cnt = (ch0 + ch2) + (ch1 + ch3);
    }
    if (half == 0 && cnt == THRANK && (!valid || cond)) th_key = key;  // unique writer
    __syncthreads();                               // B2

    // ---- P2: coef; backward from epb registers; atomic column reduction ----
    const int cm = tcnt4[0] + tcnt4[1] + tcnt4[2] + tcnt4[3];
    const float gfac  = fminf(fmaxf((float)cnt + 1.0f - a256, 0.0f), 1.0f) * (1.0f / 256.0f);
    const float g     = gfac + (ismax ? (a / (float)cm) : 0.0f);
    const float coefv = 2.0f * u * g;

    const int lbase = half * 32;                   // own wave's lanes hold these obs' coef
    float q0 = 0.f, q1 = 0.f, q2 = 0.f, q3 = 0.f;
    #pragma unroll
    for (int q = 0; q < 8; ++q) {
      q0 = fmaf(rl_f(coefv, lbase + 4 * q + 0), epb[4 * q + 0], q0);
      q1 = fmaf(rl_f(coefv, lbase + 4 * q + 1), epb[4 * q + 1], q1);
      q2 = fmaf(rl_f(coefv, lbase + 4 * q + 2), epb[4 * q + 2], q2);
      q3 = fmaf(rl_f(coefv, lbase + 4 * q + 3), epb[4 * q + 3], q3);
    }
    atomicAdd(&red[lane], (q0 + q2) + (q1 + q3));  // ds_add_f32, 8 waves -> 64 cols
    if (tid < 64) ckey[tid] = ~0ull;               // sentinel refill (slots dead until next P0)
    __syncthreads();                               // B3

    // ---- P3: step + full counting-method projection (replicated; no more barriers) ----
    const float s4 = red[lane];                    // lane j: grad_j; lane 50: sum(coef)
    cc = cc + LRATE * rl_f(s4, NY);                // gc = -sum(coef)
    const float gz = s4 - gamma * yhl;
    const float v  = zv - LRATE * gz;

    int ah0 = 0, ah1 = 0; float cs0 = 0.f, cs1 = 0.f;
    #pragma unroll
    for (int k = 0; k < NY; k += 2) {
      const float vk0 = rl_f(v, k);
      const float vk1 = rl_f(v, k + 1);
      const bool b0 = (vk0 > v) || (vk0 == v && (k    ) > lane);
      const bool b1 = (vk1 > v) || (vk1 == v && (k + 1) > lane);
      ah0 += b0 ? 1 : 0;
      ah1 += b1 ? 1 : 0;
      cs0 += b0 ? vk0 : 0.0f;
      cs1 += b1 ? vk1 : 0.0f;
    }
    const int   ahead = ah0 + ah1;
    const float css   = (cs0 + cs1) + v - 1.0f;
    const bool pc = (lane < NY) && (v - css / (float)(ahead + 1) > 0.0f);
    const int rho = __popcll(__ballot(pc));        // >= 1 always
    const unsigned long long bsel = __ballot((lane < NY) && (ahead == rho - 1));
    const int srcl = __ffsll(bsel) - 1;
    const float tau =
        __int_as_float(__builtin_amdgcn_readlane(__float_as_int(css), srcl)) / (float)rho;
    zv = (lane < NY) ? fmaxf(v - tau, 0.0f) : 0.0f;
  }

  if (tid < 64 && lane < NY) out[t * NY + lane] = zv;   // wave 0
}

extern "C" void kernel_launch(void* const* d_in, const int* in_sizes, int n_in,
                              void* d_out, int out_size, void* d_ws, size_t ws_size,
                              hipStream_t stream) {
  (void)in_sizes; (void)n_in; (void)d_ws; (void)ws_size; (void)out_size;
  const float* X   = (const float*)d_in[0];
  const float* Y   = (const float*)d_in[1];
  const float* W   = (const float*)d_in[2];
  const float* B   = (const float*)d_in[3];
  const float* DLT = (const float*)d_in[4];
  const float* GMM = (const float*)d_in[5];
  float* out = (float*)d_out;
  hipLaunchKernelGGL(dro_kernel, dim3(NOBS), dim3(512), 0, stream,
                     X, Y, W, B, DLT, GMM, out);
}

// Round 10
// 3754.703 us; speedup vs baseline: 1.1492x; 1.1492x over previous
//
#include <hip/hip_runtime.h>
#include <cfloat>
#include <math.h>

#define NOBS   256
#define NY     50
#define NX     30
#define NITER  400
#define LRATE  0.05f
#define CSTR   260     // ep_t column stride (floats), init staging
#define THRANK 40      // theta tracks the rank-40 KEY -> C = 41 every valid iter
#define WSLOT  16      // candidate slots per 64-obs window (overflow -> exact fallback)

__device__ __forceinline__ float rl_f(float x, int k) {
  return __int_as_float(__builtin_amdgcn_readlane(__float_as_int(x), k));
}
__device__ __forceinline__ unsigned long long rl_u64(unsigned long long x, int k) {
  const unsigned lo = (unsigned)__builtin_amdgcn_readlane((int)(unsigned)(x & 0xffffffffull), k);
  const unsigned hi = (unsigned)__builtin_amdgcn_readlane((int)(unsigned)(x >> 32), k);
  return ((unsigned long long)hi << 32) | lo;
}

#define DPP_MAXSTEP(x, ctrl)                                                       \
  x = fmaxf(x, __int_as_float(__builtin_amdgcn_update_dpp(                         \
        __float_as_int(x), __float_as_int(x), (ctrl), 0xF, 0xF, false)))

// One scenario/block over 8 waves (2/SIMD). Thread owns obs (tid&255) with the FULL
// 50-wide residual row in REGISTERS (R9 lesson: the rolled init loop left the er[]
// alloca dynamically indexed -> AMDGPUPromoteAlloca demoted it to LDS, +102KB LDS and
// 50 ds_read/thread/iter; full unroll -> SROA -> VGPRs). 3 barriers/iter.
__global__ __launch_bounds__(512) __attribute__((amdgpu_waves_per_eu(2, 2)))
void dro_kernel(
    const float* __restrict__ X, const float* __restrict__ Y,
    const float* __restrict__ W, const float* __restrict__ Bb,
    const float* __restrict__ DLT, const float* __restrict__ GMM,
    float* __restrict__ out)
{
  __shared__ __align__(16) float ep_t[51 * CSTR];          // init staging (dead after epb load)
  __shared__ __align__(16) unsigned long long rrk[NOBS];   // full keys (exact fallback)
  __shared__ __align__(16) unsigned long long ckey[64];    // 4 windows x 16 slots (+sentinels)
  __shared__ __align__(16) float red[64];                  // atomic backward reduction
  __shared__ float wmax4[4];
  __shared__ int   vcnt4[4];                               // candidates per window
  __shared__ int   tcnt4[4];                               // max-ties per window
  __shared__ unsigned long long th_key;

  const int tid  = threadIdx.x;      // 0..511
  const int oid  = tid & 255;        // owned observation
  const int half = tid >> 8;         // 0 = A (publisher), 1 = B (replica)
  const int lane = tid & 63;
  const int w8   = tid >> 6;         // wave 0..7
  const int wsc  = w8 & 3;           // obs window (obs wsc*64 + lane)
  const int t    = blockIdx.x;       // scenario

  const float delta = DLT[0];
  const float gamma = GMM[0];
  const float a     = fminf(delta * 0.5f, 255.0f / 256.0f);
  const float a256  = a * 256.0f;

  // ---- init: FULL residual row er[50] for owned obs, FULLY UNROLLED -> registers ----
  float er[NY];
  {
    float xr[NX];
    #pragma unroll
    for (int k = 0; k < NX; ++k) xr[k] = X[oid * NX + k];
    #pragma unroll
    for (int j = 0; j < NY; ++j) {                 // W/B wave-uniform -> scalar loads
      float acc = Bb[j];
      #pragma unroll
      for (int k = 0; k < NX; ++k) acc = fmaf(xr[k], W[j * NX + k], acc);
      er[j] = Y[oid * NY + j] - acc;
    }
    if (half == 0) {
      #pragma unroll
      for (int j = 0; j < 25; ++j) ep_t[j * CSTR + oid] = er[j];
    } else {
      #pragma unroll
      for (int j = 25; j < NY; ++j) ep_t[j * CSTR + oid] = er[j];
      ep_t[NY * CSTR + oid] = 1.0f;                // ones column -> c gradient
    }
  }
  float yhl;                                       // y_hat row t, per-lane copy
  {
    const int jr = (lane < NY) ? lane : 0;
    float acc = Bb[jr];
    #pragma unroll
    for (int k = 0; k < NX; ++k) acc = fmaf(X[t * NX + k], W[jr * NX + k], acc);
    yhl = acc;
    if (tid < NY) out[NOBS * NY + t * NY + tid] = acc;
  }
  if (tid == 0) th_key = ~0ull;                    // iter 0 -> exact fallback
  if (tid < 64) ckey[tid] = ~0ull;
  __syncthreads();

  // epb: iteration-invariant backward slice in registers.
  // Wave (half,wsc), lane l: column min(l,50), obs [wsc*64 + half*32, +32).
  float epb[32];
  {
    const int colc = (lane < 51) ? lane : 50;
    const float* ebase = &ep_t[colc * CSTR + wsc * 64 + half * 32];
    #pragma unroll
    for (int q = 0; q < 8; ++q) {
      const float4 e4 = *(const float4*)&ebase[4 * q];
      epb[4*q+0] = e4.x; epb[4*q+1] = e4.y; epb[4*q+2] = e4.z; epb[4*q+3] = e4.w;
    }
  }

  float zv = (lane < NY) ? (1.0f / NY) : 0.0f;     // z one entry/lane, replicated per wave
  float cc = 0.0f;                                 // c, wave-uniform, bit-identical everywhere

  #pragma unroll 1
  for (int it = 0; it < NITER; ++it) {
    // ---- P0: forward from OWN registers (no LDS); key; window max; candidates ----
    const unsigned long long thk = th_key;         // written P1 prev iter; B2+B3 separate
    float u0 = 0.f, u1 = 0.f, u2 = 0.f, u3 = 0.f;
    #pragma unroll
    for (int j = 0; j < 48; j += 4) {
      u0 = fmaf(er[j + 0], rl_f(zv, j + 0), u0);
      u1 = fmaf(er[j + 1], rl_f(zv, j + 1), u1);
      u2 = fmaf(er[j + 2], rl_f(zv, j + 2), u2);
      u3 = fmaf(er[j + 3], rl_f(zv, j + 3), u3);
    }
    u0 = fmaf(er[48], rl_f(zv, 48), u0);
    u1 = fmaf(er[49], rl_f(zv, 49), u1);
    const float u = ((u0 + u2) + (u1 + u3)) - cc;  // bit-identical A/B
    const float r = u * u;
    const unsigned long long key =
        ((unsigned long long)(unsigned)__float_as_int(r) << 32) | (unsigned)oid;
    if (half == 0) rrk[oid] = key;

    float m = r;                                   // window max (lanes cover obs window)
    DPP_MAXSTEP(m, 0x111); DPP_MAXSTEP(m, 0x112);
    DPP_MAXSTEP(m, 0x114); DPP_MAXSTEP(m, 0x118);
    DPP_MAXSTEP(m, 0x142); DPP_MAXSTEP(m, 0x143);
    if (half == 0 && lane == 63) wmax4[wsc] = m;

    const bool cond = (key <= thk);
    const unsigned long long cmask = __ballot(cond);
    const int cpos = __popcll(cmask & ((1ull << lane) - 1ull));
    if (half == 0 && lane == 0) vcnt4[wsc] = __popcll(cmask);
    if (half == 0 && cond && cpos < WSLOT) ckey[wsc * WSLOT + cpos] = key;  // fixed slots
    __syncthreads();                               // B1

    // ---- P1: validity; global max ties; rank scan; theta ----
    const int v0 = vcnt4[0], v1 = vcnt4[1], v2 = vcnt4[2], v3 = vcnt4[3];
    const int C  = v0 + v1 + v2 + v3;
    const bool ovf   = (v0 > WSLOT) | (v1 > WSLOT) | (v2 > WSLOT) | (v3 > WSLOT);
    const bool valid = (!ovf) && ((float)C >= a256);

    const float mx = fmaxf(fmaxf(wmax4[0], wmax4[1]), fmaxf(wmax4[2], wmax4[3]));
    const bool ismax = (r == mx);
    const unsigned long long mmask = __ballot(ismax);   // all lanes (R3 lesson)
    if (half == 0 && lane == 0) tcnt4[wsc] = __popcll(mmask);
    if (w8 == 1) red[lane] = 0.0f;                 // zero reduction buffer (single wave)

    int cnt;
    if (__builtin_expect(valid, 1)) {
      const unsigned long long ck = ckey[lane];    // all 64 slots lane-held; 1 ds_read_b64
      int ch0 = 0, ch1 = 0, ch2 = 0, ch3 = 0;
      #pragma unroll
      for (int s = 0; s < 64; s += 4) {            // sentinels never count
        ch0 += (rl_u64(ck, s + 0) < key) ? 1 : 0;
        ch1 += (rl_u64(ck, s + 1) < key) ? 1 : 0;
        ch2 += (rl_u64(ck, s + 2) < key) ? 1 : 0;
        ch3 += (rl_u64(ck, s + 3) < key) ? 1 : 0;
      }
      cnt = (ch0 + ch2) + (ch1 + ch3);             // cand: exact rank; non-cand: C (>=aN)
    } else {                                       // iter 0 / overflow: exact full scan
      int ch0 = 0, ch1 = 0, ch2 = 0, ch3 = 0;
      const ulonglong2* p = (const ulonglong2*)&rrk[0];
      #pragma unroll 8
      for (int j = 0; j < 128; j += 2) {
        const ulonglong2 ka = p[j], kb = p[j + 1];
        ch0 += (ka.x < key) ? 1 : 0;
        ch1 += (ka.y < key) ? 1 : 0;
        ch2 += (kb.x < key) ? 1 : 0;
        ch3 += (kb.y < key) ? 1 : 0;
      }
      cnt = (ch0 + ch2) + (ch1 + ch3);
    }
    if (half == 0 && cnt == THRANK && (!valid || cond)) th_key = key;  // unique writer
    __syncthreads();                               // B2

    // ---- P2: coef; backward from epb registers; atomic column reduction ----
    const int cm = tcnt4[0] + tcnt4[1] + tcnt4[2] + tcnt4[3];
    const float gfac  = fminf(fmaxf((float)cnt + 1.0f - a256, 0.0f), 1.0f) * (1.0f / 256.0f);
    const float g     = gfac + (ismax ? (a / (float)cm) : 0.0f);
    const float coefv = 2.0f * u * g;

    const int lbase = half * 32;                   // own wave's lanes hold these obs' coef
    float q0 = 0.f, q1 = 0.f, q2 = 0.f, q3 = 0.f;
    #pragma unroll
    for (int q = 0; q < 8; ++q) {
      q0 = fmaf(rl_f(coefv, lbase + 4 * q + 0), epb[4 * q + 0], q0);
      q1 = fmaf(rl_f(coefv, lbase + 4 * q + 1), epb[4 * q + 1], q1);
      q2 = fmaf(rl_f(coefv, lbase + 4 * q + 2), epb[4 * q + 2], q2);
      q3 = fmaf(rl_f(coefv, lbase + 4 * q + 3), epb[4 * q + 3], q3);
    }
    atomicAdd(&red[lane], (q0 + q2) + (q1 + q3));  // ds_add_f32, 8 waves -> 64 cols
    if (tid < 64) ckey[tid] = ~0ull;               // sentinel refill (slots dead until next P0)
    __syncthreads();                               // B3

    // ---- P3: step + full counting-method projection (replicated; no more barriers) ----
    const float s4 = red[lane];                    // lane j: grad_j; lane 50: sum(coef)
    cc = cc + LRATE * rl_f(s4, NY);                // gc = -sum(coef)
    const float gz = s4 - gamma * yhl;
    const float v  = zv - LRATE * gz;

    int ah0 = 0, ah1 = 0; float cs0 = 0.f, cs1 = 0.f;
    #pragma unroll
    for (int k = 0; k < NY; k += 2) {
      const float vk0 = rl_f(v, k);
      const float vk1 = rl_f(v, k + 1);
      const bool b0 = (vk0 > v) || (vk0 == v && (k    ) > lane);
      const bool b1 = (vk1 > v) || (vk1 == v && (k + 1) > lane);
      ah0 += b0 ? 1 : 0;
      ah1 += b1 ? 1 : 0;
      cs0 += b0 ? vk0 : 0.0f;
      cs1 += b1 ? vk1 : 0.0f;
    }
    const int   ahead = ah0 + ah1;
    const float css   = (cs0 + cs1) + v - 1.0f;
    const bool pc = (lane < NY) && (v - css / (float)(ahead + 1) > 0.0f);
    const int rho = __popcll(__ballot(pc));        // >= 1 always
    const unsigned long long bsel = __ballot((lane < NY) && (ahead == rho - 1));
    const int srcl = __ffsll(bsel) - 1;
    const float tau =
        __int_as_float(__builtin_amdgcn_readlane(__float_as_int(css), srcl)) / (float)rho;
    zv = (lane < NY) ? fmaxf(v - tau, 0.0f) : 0.0f;
  }

  if (tid < 64 && lane < NY) out[t * NY + lane] = zv;   // wave 0
}

extern "C" void kernel_launch(void* const* d_in, const int* in_sizes, int n_in,
                              void* d_out, int out_size, void* d_ws, size_t ws_size,
                              hipStream_t stream) {
  (void)in_sizes; (void)n_in; (void)d_ws; (void)ws_size; (void)out_size;
  const float* X   = (const float*)d_in[0];
  const float* Y   = (const float*)d_in[1];
  const float* W   = (const float*)d_in[2];
  const float* B   = (const float*)d_in[3];
  const float* DLT = (const float*)d_in[4];
  const float* GMM = (const float*)d_in[5];
  float* out = (float*)d_out;
  hipLaunchKernelGGL(dro_kernel, dim3(NOBS), dim3(512), 0, stream,
                     X, Y, W, B, DLT, GMM, out);
}